// Round 16
// baseline (66.312 us; speedup 1.0000x reference)
//
#include <hip/hip_runtime.h>

#define NUM_BINS  512
#define NUM_NODES 128
#define K_ELEMS   16384
#define N_PAIRS   1024
#define NCOPY     16
#define LIST_MAX  320

typedef float f32x4 __attribute__((ext_vector_type(4)));
typedef float f32x2 __attribute__((ext_vector_type(2)));
typedef unsigned int   u32;
typedef unsigned short u16;

// ---------------------------------------------------------------------------
// Pass 1: per-row histogram -> PRIVATE rowhist (u32 fixed-point, plain
// coalesced stores). No global atomics, no zero pass needed (rowhist/rowwsum/
// mask are fully overwritten each call). LDS: 16-copy u32 hist, ds_add_u32
// (fast bank-parallel path; ds_add_f32 is CU-serialized, R1-R4). 512 thr +
// 32 KB LDS -> 4 blocks/CU, depth-2 prefetch. Writes 2 MiB validity bitmask.
// Weights nt (read-once); residuals cacheable (lookup re-reads them).
// ---------------------------------------------------------------------------
__global__ __launch_bounds__(512) void hist_kernel(
    const float* __restrict__ residuals, const float* __restrict__ weights,
    u32* __restrict__ rowhist, float* __restrict__ rowwsum,
    u32* __restrict__ mask)
{
    __shared__ u32 lh[NUM_BINS * NCOPY];   // 32768 B
    __shared__ float swsum[8];
    const int row  = blockIdx.x;
    const int t    = threadIdx.x;          // 0..511
    const int copy = t & 15;

    uint4* lh4 = (uint4*)lh;
    #pragma unroll
    for (int k = 0; k < NUM_BINS * NCOPY / 4 / 512; ++k) {   // 4
        uint4 z; z.x = z.y = z.z = z.w = 0u;
        lh4[t + k * 512] = z;
    }
    __syncthreads();

    const f32x4* r4 = (const f32x4*)(residuals + (size_t)row * K_ELEMS);
    const f32x4* w4 = (const f32x4*)(weights   + (size_t)row * K_ELEMS);

    float wsum = 0.0f;
    u32 vbits = 0;

    f32x4 rA = r4[t];
    f32x4 wA = __builtin_nontemporal_load(w4 + t);
    #pragma unroll
    for (int it = 0; it < K_ELEMS / 4 / 512; ++it) {   // 8 iters
        f32x4 rB, wB;
        if (it < K_ELEMS / 4 / 512 - 1) {
            rB = r4[t + (it + 1) * 512];
            wB = __builtin_nontemporal_load(w4 + (t + (it + 1) * 512));
        }
        wsum += wA[0] + wA[1] + wA[2] + wA[3];     // tw is UNMASKED sum
        #pragma unroll
        for (int c = 0; c < 4; ++c) {
            int b = (int)floorf(rA[c] * 512.0f);
            if ((unsigned)b < 512u)
                atomicAdd(&lh[b * NCOPY + copy], (u32)fmaf(wA[c], 65536.0f, 0.5f));
            int lb = (int)floorf(rA[c] * 512.0f + 0.5f);
            if (((unsigned)lb < 512u) & (wA[c] > 0.0f))
                vbits |= 1u << (it * 4 + c);
        }
        rA = rB; wA = wB;
    }
    mask[(size_t)row * 512 + t] = vbits;

    #pragma unroll
    for (int off = 32; off > 0; off >>= 1) wsum += __shfl_down(wsum, off, 64);
    const int wave = t >> 6, lane = t & 63;
    if (lane == 0) swsum[wave] = wsum;
    __syncthreads();

    if (t == 0) {
        float tot = 0.0f;
        #pragma unroll
        for (int i = 0; i < 8; ++i) tot += swsum[i];
        rowwsum[row] = tot;
    }

    // flush: thread t owns bin t; rotated copy reads (2 lanes/bank), plain
    // coalesced u32 store -- no atomics.
    {
        u32 tot = 0;
        #pragma unroll
        for (int cc = 0; cc < NCOPY; ++cc)
            tot += lh[t * NCOPY + ((t + cc) & 15)];
        rowhist[(size_t)row * NUM_BINS + t] = tot;
    }
}

// ---------------------------------------------------------------------------
// Pass 2 (gather + scan + lookup): one block (512 thr) per row.
//  - issue-early: 8 residual vec-loads + mask word (latency hides under the
//    list build / gather / scan)
//  - stage src/dst/rowwsum in LDS; build compact row lists for nodes s and d
//    (LDS u32-atomic append; a row appears once per match, so src==dst rows
//    count twice -- matches ref's double segment_sum)
//  - gather: accS/accD[bin t] = SUM u32 rowhist[r'][t] over list (coalesced
//    2 KB loads from the L2-resident 2 MiB rowhist; u32 add = order-exact)
//  - tw: deterministic block tree-reduction of masked rowwsum
//  - pmf -> f32x2 Hillis-Steele scan (same add order as R15) -> emit with
//    bin recompute + validity mask, nt-stores.
// ---------------------------------------------------------------------------
__global__ __launch_bounds__(512) void lookup_scan_kernel(
    const float* __restrict__ residuals, const u32* __restrict__ mask,
    const int* __restrict__ src, const int* __restrict__ dst,
    const u32* __restrict__ rowhist, const float* __restrict__ rowwsum,
    float* __restrict__ out_src, float* __restrict__ out_dst)
{
    __shared__ f32x2 sd[NUM_BINS];          // 4 KB
    __shared__ int   ssrc[N_PAIRS];         // 4 KB
    __shared__ int   sdst[N_PAIRS];         // 4 KB
    __shared__ float rw[N_PAIRS];           // 4 KB
    __shared__ u16   listS[LIST_MAX], listD[LIST_MAX];
    __shared__ u32   cntS, cntD;
    __shared__ float twsh[16];

    const int row = blockIdx.x;
    const int t   = threadIdx.x;            // 0..511

    const size_t base = (size_t)row * K_ELEMS;
    const f32x4* r4   = (const f32x4*)(residuals + base);

    // issue-early
    f32x4 rr0 = r4[t],        rr1 = r4[t + 512];
    f32x4 rr2 = r4[t + 1024], rr3 = r4[t + 1536];
    f32x4 rr4 = r4[t + 2048], rr5 = r4[t + 2560];
    f32x4 rr6 = r4[t + 3072], rr7 = r4[t + 3584];
    const u32 mw = mask[(size_t)row * 512 + t];

    if (t == 0) { cntS = 0; cntD = 0; }
    ssrc[t] = src[t];  ssrc[t + 512] = src[t + 512];
    sdst[t] = dst[t];  sdst[t + 512] = dst[t + 512];
    rw[t] = rowwsum[t]; rw[t + 512] = rowwsum[t + 512];
    __syncthreads();

    const int s = ssrc[row], d = sdst[row];

    // build lists + tw partials (each thread: rows t and t+512)
    float pS = 0.0f, pD = 0.0f;
    #pragma unroll
    for (int h = 0; h < 2; ++h) {
        const int r = t + h * 512;
        const int rs = ssrc[r], rd = sdst[r];
        const float w = rw[r];
        if (rs == s) { u32 i = atomicAdd(&cntS, 1u); if (i < LIST_MAX) listS[i] = (u16)r; pS += w; }
        if (rd == s) { u32 i = atomicAdd(&cntS, 1u); if (i < LIST_MAX) listS[i] = (u16)r; pS += w; }
        if (rs == d) { u32 i = atomicAdd(&cntD, 1u); if (i < LIST_MAX) listD[i] = (u16)r; pD += w; }
        if (rd == d) { u32 i = atomicAdd(&cntD, 1u); if (i < LIST_MAX) listD[i] = (u16)r; pD += w; }
    }
    // deterministic tree-reduce tw partials
    #pragma unroll
    for (int off = 32; off > 0; off >>= 1) {
        pS += __shfl_down(pS, off, 64);
        pD += __shfl_down(pD, off, 64);
    }
    if ((t & 63) == 0) { twsh[(t >> 6) * 2] = pS; twsh[(t >> 6) * 2 + 1] = pD; }
    __syncthreads();

    float twS = 0.0f, twD = 0.0f;
    #pragma unroll
    for (int i = 0; i < 8; ++i) { twS += twsh[i * 2]; twD += twsh[i * 2 + 1]; }

    // gather node histograms (u32, order-exact); lists uniform across block
    const int nS = (int)min(cntS, (u32)LIST_MAX);
    const int nD = (int)min(cntD, (u32)LIST_MAX);
    u32 accS = 0, accD = 0;
    {
        int i = 0;
        for (; i + 4 <= nS; i += 4) {
            u32 a0 = rowhist[(size_t)listS[i]     * NUM_BINS + t];
            u32 a1 = rowhist[(size_t)listS[i + 1] * NUM_BINS + t];
            u32 a2 = rowhist[(size_t)listS[i + 2] * NUM_BINS + t];
            u32 a3 = rowhist[(size_t)listS[i + 3] * NUM_BINS + t];
            accS += a0 + a1 + a2 + a3;
        }
        for (; i < nS; ++i) accS += rowhist[(size_t)listS[i] * NUM_BINS + t];
    }
    {
        int i = 0;
        for (; i + 4 <= nD; i += 4) {
            u32 a0 = rowhist[(size_t)listD[i]     * NUM_BINS + t];
            u32 a1 = rowhist[(size_t)listD[i + 1] * NUM_BINS + t];
            u32 a2 = rowhist[(size_t)listD[i + 2] * NUM_BINS + t];
            u32 a3 = rowhist[(size_t)listD[i + 3] * NUM_BINS + t];
            accD += a0 + a1 + a2 + a3;
        }
        for (; i < nD; ++i) accD += rowhist[(size_t)listD[i] * NUM_BINS + t];
    }

    // pmf -> scan
    {
        f32x2 v;
        v[0] = (float)accS * (1.0f / 65536.0f) / (twS + 1e-10f);
        v[1] = (float)accD * (1.0f / 65536.0f) / (twD + 1e-10f);
        sd[t] = v;
    }
    __syncthreads();

    for (int off = 1; off < NUM_BINS; off <<= 1) {
        f32x2 add = (t >= off) ? sd[t - off] : (f32x2){0.0f, 0.0f};
        __syncthreads();
        sd[t] += add;
        __syncthreads();
    }

    f32x4* os4 = (f32x4*)(out_src + base);
    f32x4* od4 = (f32x4*)(out_dst + base);

    #define EMIT(IT, RV)                                                       \
    {                                                                          \
        f32x4 osv, odv;                                                        \
        _Pragma("unroll")                                                      \
        for (int c = 0; c < 4; ++c) {                                          \
            int lb = (int)floorf(RV[c] * 512.0f + 0.5f);                       \
            int bc = min(max(lb, 0), NUM_BINS - 1);                            \
            bool v = (mw >> (IT * 4 + c)) & 1u;                                \
            f32x2 vv = v ? sd[bc] : (f32x2){2.0f, 2.0f};                       \
            osv[c] = vv[0]; odv[c] = vv[1];                                    \
        }                                                                      \
        __builtin_nontemporal_store(osv, os4 + (t + IT * 512));                \
        __builtin_nontemporal_store(odv, od4 + (t + IT * 512));                \
    }
    EMIT(0, rr0) EMIT(1, rr1) EMIT(2, rr2) EMIT(3, rr3)
    EMIT(4, rr4) EMIT(5, rr5) EMIT(6, rr6) EMIT(7, rr7)
    #undef EMIT
}

// ---------------------------------------------------------------------------
extern "C" void kernel_launch(void* const* d_in, const int* in_sizes, int n_in,
                              void* d_out, int out_size, void* d_ws, size_t ws_size,
                              hipStream_t stream)
{
    const float* residuals = (const float*)d_in[0];
    const float* weights   = (const float*)d_in[1];
    const int*   src       = (const int*)d_in[2];
    const int*   dst       = (const int*)d_in[3];

    float* out_src = (float*)d_out;
    float* out_dst = out_src + (size_t)N_PAIRS * K_ELEMS;

    // ws: rowhist u32[1024][512] (2 MiB) at 0; rowwsum f32[1024] at 2 MiB;
    // mask u32[1024*512] (2 MiB) at 4 MiB. All fully overwritten every call
    // -> no zero pass.
    u32*   rowhist = (u32*)d_ws;
    float* rowwsum = (float*)((char*)d_ws + (2u << 20));
    u32*   mask    = (u32*)((char*)d_ws + (4u << 20));

    hist_kernel<<<N_PAIRS, 512, 0, stream>>>(residuals, weights,
                                             rowhist, rowwsum, mask);

    lookup_scan_kernel<<<N_PAIRS, 512, 0, stream>>>(residuals, mask, src, dst,
                                                    rowhist, rowwsum,
                                                    out_src, out_dst);
}

// Round 17
// 64.091 us; speedup vs baseline: 1.0347x; 1.0347x over previous
//
#include <hip/hip_runtime.h>

#define NUM_BINS  512
#define NUM_NODES 128
#define K_ELEMS   16384
#define N_PAIRS   1024
#define NCOPY     16

typedef float f32x4 __attribute__((ext_vector_type(4)));
typedef float f32x2 __attribute__((ext_vector_type(2)));
typedef unsigned int   u32;
typedef unsigned short u16;

__device__ __forceinline__ void gfadd(float* p, float v) { unsafeAtomicAdd(p, v); }

// ---------------------------------------------------------------------------
// Pass 0: zero node hist + tw (65,664 floats, ~1us).
// ---------------------------------------------------------------------------
__global__ __launch_bounds__(256) void zero_ws_kernel(float* __restrict__ ws, int n)
{
    int i = blockIdx.x * 256 + threadIdx.x;
    if (i < n) ws[i] = 0.0f;
}

// ---------------------------------------------------------------------------
// Pass 1: per-row histogram. Fixed-point u32 LDS atomics (ds_add_u32 = fast
// bank-parallel path; ds_add_f32 is CU-serialized, measured R1-R4).
// 512 thr + NCOPY=16 (32 KB LDS) -> 4 blocks/CU x 8 waves = 32 waves/CU with
// VGPR budget 128 -> depth-2 prefetch. Worst-case LDS atomic aliasing 4-way
// (atomic op only). Writes 2 MiB u32 validity bitmask; weights nt
// (read-once), residuals cacheable (lookup re-reads them).
// ---------------------------------------------------------------------------
__global__ __launch_bounds__(512) void hist_kernel(
    const float* __restrict__ residuals, const float* __restrict__ weights,
    const int* __restrict__ src, const int* __restrict__ dst,
    float* __restrict__ hist, float* __restrict__ tw,
    u32* __restrict__ mask)
{
    __shared__ u32 lh[NUM_BINS * NCOPY];   // 32768 B
    __shared__ float swsum[8];
    const int row  = blockIdx.x;
    const int t    = threadIdx.x;          // 0..511
    const int copy = t & 15;

    uint4* lh4 = (uint4*)lh;
    #pragma unroll
    for (int k = 0; k < NUM_BINS * NCOPY / 4 / 512; ++k) {   // 4
        uint4 z; z.x = z.y = z.z = z.w = 0u;
        lh4[t + k * 512] = z;
    }
    __syncthreads();

    const f32x4* r4 = (const f32x4*)(residuals + (size_t)row * K_ELEMS);
    const f32x4* w4 = (const f32x4*)(weights   + (size_t)row * K_ELEMS);

    float wsum = 0.0f;
    u32 vbits = 0;

    // depth-2 software prefetch over 8 iterations
    f32x4 rA = r4[t];
    f32x4 wA = __builtin_nontemporal_load(w4 + t);
    #pragma unroll
    for (int it = 0; it < K_ELEMS / 4 / 512; ++it) {   // 8 iters
        f32x4 rB, wB;
        if (it < K_ELEMS / 4 / 512 - 1) {
            rB = r4[t + (it + 1) * 512];
            wB = __builtin_nontemporal_load(w4 + (t + (it + 1) * 512));
        }
        wsum += wA[0] + wA[1] + wA[2] + wA[3];     // tw is UNMASKED sum
        #pragma unroll
        for (int c = 0; c < 4; ++c) {
            int b = (int)floorf(rA[c] * 512.0f);
            if ((unsigned)b < 512u)
                atomicAdd(&lh[b * NCOPY + copy], (u32)fmaf(wA[c], 65536.0f, 0.5f));
            int lb = (int)floorf(rA[c] * 512.0f + 0.5f);
            if (((unsigned)lb < 512u) & (wA[c] > 0.0f))
                vbits |= 1u << (it * 4 + c);
        }
        rA = rB; wA = wB;
    }
    mask[(size_t)row * 512 + t] = vbits;

    #pragma unroll
    for (int off = 32; off > 0; off >>= 1) wsum += __shfl_down(wsum, off, 64);
    const int wave = t >> 6, lane = t & 63;
    if (lane == 0) swsum[wave] = wsum;
    __syncthreads();

    const int s = src[row], d = dst[row];
    if (t == 0) {
        float tot = 0.0f;
        #pragma unroll
        for (int i = 0; i < 8; ++i) tot += swsum[i];
        gfadd(&tw[s], tot);
        gfadd(&tw[d], tot);   // both, even if s == d (matches ref)
    }

    // flush: thread t owns bin t; rotated copy index; coalesced f32 atomics.
    {
        u32 tot = 0;
        #pragma unroll
        for (int cc = 0; cc < NCOPY; ++cc)
            tot += lh[t * NCOPY + ((t + cc) & 15)];
        float v = (float)tot * (1.0f / 65536.0f);
        gfadd(&hist[s * NUM_BINS + t], v);
        gfadd(&hist[d * NUM_BINS + t], v);
    }
}

// ---------------------------------------------------------------------------
// Pass 2 (fused scan+lookup): one block (512 thr) per row.
//  - issue ALL residual re-read loads FIRST (issue-early): latency hides
//    under the scan's ~20 barriers
//  - stage {hist[s][t]/denom_s, hist[d][t]/denom_d} as f32x2, Hillis-Steele
//    scan -> bitwise-identical cdf to the standalone scan kernel
//  - recompute bin from residual, validity from u32 mask, nt-store outputs.
// Mask bit for elem 4*(t+it*512)+c is it*4+c of word mask[row*512+t].
// ---------------------------------------------------------------------------
__global__ __launch_bounds__(512) void lookup_scan_kernel(
    const float* __restrict__ residuals, const u32* __restrict__ mask,
    const int* __restrict__ src, const int* __restrict__ dst,
    const float* __restrict__ hist, const float* __restrict__ tw,
    float* __restrict__ out_src, float* __restrict__ out_dst)
{
    __shared__ f32x2 sd[NUM_BINS];          // {src_cdf, dst_cdf} per bin
    const int row = blockIdx.x;
    const int t   = threadIdx.x;            // 0..511

    const size_t base = (size_t)row * K_ELEMS;
    const f32x4* r4   = (const f32x4*)(residuals + base);

    // issue-early: all 8 residual vec-loads + the mask word
    f32x4 rr0 = r4[t],           rr1 = r4[t + 512];
    f32x4 rr2 = r4[t + 1024],    rr3 = r4[t + 1536];
    f32x4 rr4 = r4[t + 2048],    rr5 = r4[t + 2560];
    f32x4 rr6 = r4[t + 3072],    rr7 = r4[t + 3584];
    const u32 mw = mask[(size_t)row * 512 + t];

    const int s = src[row], d = dst[row];
    {
        f32x2 v;
        v[0] = hist[s * NUM_BINS + t] / (tw[s] + 1e-10f);
        v[1] = hist[d * NUM_BINS + t] / (tw[d] + 1e-10f);
        sd[t] = v;
    }
    __syncthreads();

    for (int off = 1; off < NUM_BINS; off <<= 1) {
        f32x2 add = (t >= off) ? sd[t - off] : (f32x2){0.0f, 0.0f};
        __syncthreads();
        sd[t] += add;
        __syncthreads();
    }

    f32x4* os4 = (f32x4*)(out_src + base);
    f32x4* od4 = (f32x4*)(out_dst + base);

    #define EMIT(IT, RV)                                                       \
    {                                                                          \
        f32x4 osv, odv;                                                        \
        _Pragma("unroll")                                                      \
        for (int c = 0; c < 4; ++c) {                                          \
            int lb = (int)floorf(RV[c] * 512.0f + 0.5f);                       \
            int bc = min(max(lb, 0), NUM_BINS - 1);                            \
            bool v = (mw >> (IT * 4 + c)) & 1u;                                \
            f32x2 vv = v ? sd[bc] : (f32x2){2.0f, 2.0f};                       \
            osv[c] = vv[0]; odv[c] = vv[1];                                    \
        }                                                                      \
        __builtin_nontemporal_store(osv, os4 + (t + IT * 512));                \
        __builtin_nontemporal_store(odv, od4 + (t + IT * 512));                \
    }
    EMIT(0, rr0) EMIT(1, rr1) EMIT(2, rr2) EMIT(3, rr3)
    EMIT(4, rr4) EMIT(5, rr5) EMIT(6, rr6) EMIT(7, rr7)
    #undef EMIT
}

// ---------------------------------------------------------------------------
extern "C" void kernel_launch(void* const* d_in, const int* in_sizes, int n_in,
                              void* d_out, int out_size, void* d_ws, size_t ws_size,
                              hipStream_t stream)
{
    const float* residuals = (const float*)d_in[0];
    const float* weights   = (const float*)d_in[1];
    const int*   src       = (const int*)d_in[2];
    const int*   dst       = (const int*)d_in[3];

    float* out_src = (float*)d_out;
    float* out_dst = out_src + (size_t)N_PAIRS * K_ELEMS;

    // ws: hist f32[128][512], tw f32[128] contiguous; mask u32[1024*512]
    // (2 MiB) at +4 MiB.
    float* hist = (float*)d_ws;
    float* tw   = hist + NUM_NODES * NUM_BINS;
    u32*   mask = (u32*)((char*)d_ws + (4u << 20));

    const int ws_elems = NUM_NODES * NUM_BINS + NUM_NODES;
    zero_ws_kernel<<<(ws_elems + 255) / 256, 256, 0, stream>>>((float*)d_ws, ws_elems);

    hist_kernel<<<N_PAIRS, 512, 0, stream>>>(residuals, weights, src, dst,
                                             hist, tw, mask);

    lookup_scan_kernel<<<N_PAIRS, 512, 0, stream>>>(residuals, mask, src, dst,
                                                    hist, tw, out_src, out_dst);
}